// Round 1
// baseline (267.908 us; speedup 1.0000x reference)
//
#include <hip/hip_runtime.h>

// Round 1: full pipeline — cvt(bf16) -> QKV GEMM(MFMA, scatter epilogue)
//          -> flash attention (16-row wave tiles, online softmax)
//          -> proj GEMM -> f32 out.
// Constants for this problem:
//   B=8 N=1024 C=768 H=12 D=64 P=16; BH=96; padded KV len MKV=1056, valid=1040.

typedef __attribute__((ext_vector_type(8))) short short8;
typedef __attribute__((ext_vector_type(4))) float f32x4;

#define GLOAD_LDS16(g, l)                                              \
    __builtin_amdgcn_global_load_lds(                                  \
        (const __attribute__((address_space(1))) void*)(g),            \
        (__attribute__((address_space(3))) void*)(l), 16, 0, 0)

__device__ __forceinline__ unsigned short f2b(float f) {
    unsigned u = __builtin_bit_cast(unsigned, f);
    u = (u + 0x7fffu + ((u >> 16) & 1u)) >> 16;
    return (unsigned short)u;
}

// ---------------- f32 -> bf16 convert (vectorized) ----------------
__global__ void cvt_f32_to_bf16(const float* __restrict__ in,
                                unsigned short* __restrict__ out, int n4) {
    int i = blockIdx.x * blockDim.x + threadIdx.x;
    int stride = gridDim.x * blockDim.x;
    for (; i < n4; i += stride) {
        float4 v = reinterpret_cast<const float4*>(in)[i];
        ushort4 o;
        o.x = f2b(v.x); o.y = f2b(v.y); o.z = f2b(v.z); o.w = f2b(v.w);
        reinterpret_cast<ushort4*>(out)[i] = o;
    }
}

// ------------- prefix K/V prefill + pad-row zeroing ----------------
// kc: [96][1056][64]  rows 0..15 = prefix, 1040..1055 = zero pad
// vT: [96][64][1056]  cols 0..15 = prefix, 1040..1055 = zero pad
__global__ void prefill(const float* __restrict__ pk, const float* __restrict__ pv,
                        unsigned short* __restrict__ kc, unsigned short* __restrict__ vT) {
    int idx = blockIdx.x * 256 + threadIdx.x;   // 96*32*64 total
    int d  = idx & 63;
    int j  = (idx >> 6) & 31;
    int bh = idx >> 11;
    if (bh >= 96) return;
    int h = bh % 12;
    if (j < 16) {
        kc[((size_t)bh * 1056 + j) * 64 + d]  = f2b(pk[j * 768 + h * 64 + d]);
        vT[((size_t)bh * 64 + d) * 1056 + j]  = f2b(pv[j * 768 + h * 64 + d]);
    } else {
        int row = 1040 + (j - 16);
        kc[((size_t)bh * 1056 + row) * 64 + d] = 0;
        vT[((size_t)bh * 64 + d) * 1056 + row] = 0;
    }
}

// ---------------- GEMM:  Y[m][f] = sum_k A[m][k] * W[f][k] + bias[f] ----------------
// 128x128 tile, BK=32, 4 waves (2x2), wave tile 64x64, mfma 16x16x32 bf16.
// MODE 0: QKV epilogue scatter (q scaled, k into kc rows 16.., v transposed into vT)
// MODE 1: plain f32 output [M][F]
template<int MODE>
__global__ __launch_bounds__(256) void gemm_bt(
    const unsigned short* __restrict__ A,   // [M][K] bf16
    const unsigned short* __restrict__ W,   // [F][K] bf16
    const float* __restrict__ bias,         // [F]
    int M, int F, int K,
    unsigned short* __restrict__ qbuf,      // [96][1024][64]
    unsigned short* __restrict__ kcbuf,     // [96][1056][64]
    unsigned short* __restrict__ vtbuf,     // [96][64][1056]
    float* __restrict__ fout)               // [M][F]
{
    __shared__ __align__(16) unsigned short As[128 * 32];
    __shared__ __align__(16) unsigned short Ws[128 * 32];

    const int tid = threadIdx.x;
    const int m0 = blockIdx.y * 128;
    const int f0 = blockIdx.x * 128;
    const int wid = tid >> 6, lane = tid & 63;
    const int wr = wid >> 1, wc = wid & 1;
    const int lo = lane & 15, hi = lane >> 4;

    f32x4 acc[4][4];
#pragma unroll
    for (int i = 0; i < 4; ++i)
#pragma unroll
        for (int j = 0; j < 4; ++j) acc[i][j] = (f32x4)0.f;

    for (int k0 = 0; k0 < K; k0 += 32) {
#pragma unroll
        for (int j = 0; j < 2; ++j) {
            int e = j * 256 + tid;          // 0..511, lane-contiguous per wave
            int row = e >> 2, c8 = (e & 3) * 8;
            GLOAD_LDS16(A + (size_t)(m0 + row) * K + k0 + c8, As + e * 8);
            GLOAD_LDS16(W + (size_t)(f0 + row) * K + k0 + c8, Ws + e * 8);
        }
        __syncthreads();

        short8 av[4], wv[4];
#pragma unroll
        for (int mi = 0; mi < 4; ++mi)
            av[mi] = *reinterpret_cast<const short8*>(&As[(wr * 64 + mi * 16 + lo) * 32 + hi * 8]);
#pragma unroll
        for (int ni = 0; ni < 4; ++ni)
            wv[ni] = *reinterpret_cast<const short8*>(&Ws[(wc * 64 + ni * 16 + lo) * 32 + hi * 8]);
#pragma unroll
        for (int mi = 0; mi < 4; ++mi)
#pragma unroll
            for (int ni = 0; ni < 4; ++ni)
                acc[mi][ni] = __builtin_amdgcn_mfma_f32_16x16x32_bf16(av[mi], wv[ni], acc[mi][ni], 0, 0, 0);
        __syncthreads();
    }

    // epilogue: D row = hi*4 + r, col = lo  (within each 16x16 tile)
#pragma unroll
    for (int mi = 0; mi < 4; ++mi) {
#pragma unroll
        for (int ni = 0; ni < 4; ++ni) {
            int f = f0 + wc * 64 + ni * 16 + lo;
            float bv = bias[f];
#pragma unroll
            for (int r = 0; r < 4; ++r) {
                int m = m0 + wr * 64 + mi * 16 + hi * 4 + r;
                float val = acc[mi][ni][r] + bv;
                if (MODE == 1) {
                    fout[(size_t)m * F + f] = val;
                } else {
                    int b = m >> 10, n = m & 1023;
                    if (f < 768) {
                        int h = f >> 6, d = f & 63;
                        qbuf[((size_t)(b * 12 + h) * 1024 + n) * 64 + d] = f2b(val * 0.125f);
                    } else if (f < 1536) {
                        int f2 = f - 768; int h = f2 >> 6, d = f2 & 63;
                        kcbuf[((size_t)(b * 12 + h) * 1056 + 16 + n) * 64 + d] = f2b(val);
                    } else {
                        int f2 = f - 1536; int h = f2 >> 6, d = f2 & 63;
                        vtbuf[((size_t)(b * 12 + h) * 64 + d) * 1056 + 16 + n] = f2b(val);
                    }
                }
            }
        }
    }
}

// ---------------- flash attention ----------------
// 1 wave = 16 q rows x full D=64. Keys looped in tiles of 32 (33 tiles, mask >=1040).
__global__ __launch_bounds__(256) void attn_kernel(
    const unsigned short* __restrict__ q,   // [96][1024][64] (pre-scaled)
    const unsigned short* __restrict__ kc,  // [96][1056][64]
    const unsigned short* __restrict__ vT,  // [96][64][1056]
    unsigned short* __restrict__ ao)        // [8][1024][768]
{
    __shared__ __align__(16) unsigned short pb[4][16 * 40];  // padded stride 40

    const int tid = threadIdx.x;
    const int w = tid >> 6, lane = tid & 63;
    const int lo = lane & 15, hi = lane >> 4;
    const int gw = blockIdx.x * 4 + w;      // 0..6143
    const int bh = gw >> 6;
    const int qt = gw & 63;
    const int b = bh / 12, h = bh % 12;

    const unsigned short* qp = q + ((size_t)bh * 1024 + qt * 16) * 64;
    const unsigned short* kp = kc + (size_t)bh * 1056 * 64;
    const unsigned short* vp = vT + (size_t)bh * 64 * 1056;

    short8 qf[2];
#pragma unroll
    for (int ks = 0; ks < 2; ++ks)
        qf[ks] = *reinterpret_cast<const short8*>(qp + (size_t)lo * 64 + ks * 32 + hi * 8);

    f32x4 o[4];
#pragma unroll
    for (int di = 0; di < 4; ++di) o[di] = (f32x4)0.f;
    float mrow[4] = {-1e30f, -1e30f, -1e30f, -1e30f};
    float lrow[4] = {0.f, 0.f, 0.f, 0.f};

    unsigned short* pw = &pb[w][0];

    for (int t = 0; t < 33; ++t) {
        const int kbase = t * 32;
        f32x4 s[2];
#pragma unroll
        for (int ct = 0; ct < 2; ++ct) {
            s[ct] = (f32x4)0.f;
#pragma unroll
            for (int ks = 0; ks < 2; ++ks) {
                short8 kf = *reinterpret_cast<const short8*>(
                    kp + (size_t)(kbase + ct * 16 + lo) * 64 + ks * 32 + hi * 8);
                s[ct] = __builtin_amdgcn_mfma_f32_16x16x32_bf16(qf[ks], kf, s[ct], 0, 0, 0);
            }
        }
        // mask invalid keys (>= 1040)
#pragma unroll
        for (int ct = 0; ct < 2; ++ct) {
            int key = kbase + ct * 16 + lo;
            if (key >= 1040) {
#pragma unroll
                for (int r = 0; r < 4; ++r) s[ct][r] = -1e30f;
            }
        }
        // online softmax (rows hi*4+r spread over the 16 lanes sharing hi)
#pragma unroll
        for (int r = 0; r < 4; ++r) {
            float tm = fmaxf(s[0][r], s[1][r]);
            tm = fmaxf(tm, __shfl_xor(tm, 1));
            tm = fmaxf(tm, __shfl_xor(tm, 2));
            tm = fmaxf(tm, __shfl_xor(tm, 4));
            tm = fmaxf(tm, __shfl_xor(tm, 8));
            float mn = fmaxf(mrow[r], tm);
            float cf = __expf(mrow[r] - mn);
            float p0 = __expf(s[0][r] - mn);
            float p1 = __expf(s[1][r] - mn);
            float ps = p0 + p1;
            ps += __shfl_xor(ps, 1);
            ps += __shfl_xor(ps, 2);
            ps += __shfl_xor(ps, 4);
            ps += __shfl_xor(ps, 8);
            lrow[r] = lrow[r] * cf + ps;
            mrow[r] = mn;
#pragma unroll
            for (int di = 0; di < 4; ++di) o[di][r] *= cf;
            pw[(hi * 4 + r) * 40 + lo]      = f2b(p0);
            pw[(hi * 4 + r) * 40 + 16 + lo] = f2b(p1);
        }
        asm volatile("s_waitcnt lgkmcnt(0)" ::: "memory");
        short8 pf = *reinterpret_cast<const short8*>(pw + lo * 40 + hi * 8);
#pragma unroll
        for (int di = 0; di < 4; ++di) {
            short8 vf = *reinterpret_cast<const short8*>(
                vp + (size_t)(di * 16 + lo) * 1056 + kbase + hi * 8);
            o[di] = __builtin_amdgcn_mfma_f32_16x16x32_bf16(pf, vf, o[di], 0, 0, 0);
        }
    }

    float rinv[4];
#pragma unroll
    for (int r = 0; r < 4; ++r) rinv[r] = 1.f / lrow[r];
    unsigned short* aop = ao + ((size_t)b * 1024 + qt * 16) * 768 + h * 64;
#pragma unroll
    for (int di = 0; di < 4; ++di)
#pragma unroll
        for (int r = 0; r < 4; ++r)
            aop[(size_t)(hi * 4 + r) * 768 + di * 16 + lo] = f2b(o[di][r] * rinv[r]);
}

extern "C" void kernel_launch(void* const* d_in, const int* in_sizes, int n_in,
                              void* d_out, int out_size, void* d_ws, size_t ws_size,
                              hipStream_t stream) {
    const float* x        = (const float*)d_in[0];
    const float* qkv_w    = (const float*)d_in[1];
    const float* qkv_b    = (const float*)d_in[2];
    const float* proj_w   = (const float*)d_in[3];
    const float* proj_b   = (const float*)d_in[4];
    const float* prefix_k = (const float*)d_in[5];
    const float* prefix_v = (const float*)d_in[6];
    float* out = (float*)d_out;

    char* ws = (char*)d_ws;
    unsigned short* xb   = (unsigned short*)(ws);               // 8192*768 bf16 (12.58 MB)
    unsigned short* wqkv = (unsigned short*)(ws + 12582912);    // 2304*768
    unsigned short* wp   = (unsigned short*)(ws + 16121856);    // 768*768
    unsigned short* qb   = (unsigned short*)(ws + 17301504);    // 96*1024*64
    unsigned short* kcb  = (unsigned short*)(ws + 29884416);    // 96*1056*64
    unsigned short* vtb  = (unsigned short*)(ws + 42860544);    // 96*64*1056 (ends 55.8MB)
    unsigned short* aob  = xb;                                  // reuse xb after QKV GEMM

    cvt_f32_to_bf16<<<1024, 256, 0, stream>>>(x, xb, 8192 * 768 / 4);
    cvt_f32_to_bf16<<<512, 256, 0, stream>>>(qkv_w, wqkv, 2304 * 768 / 4);
    cvt_f32_to_bf16<<<256, 256, 0, stream>>>(proj_w, wp, 768 * 768 / 4);
    prefill<<<768, 256, 0, stream>>>(prefix_k, prefix_v, kcb, vtb);

    gemm_bt<0><<<dim3(18, 64), 256, 0, stream>>>(xb, wqkv, qkv_b, 8192, 2304, 768,
                                                 qb, kcb, vtb, nullptr);
    attn_kernel<<<1536, 256, 0, stream>>>(qb, kcb, vtb, aob);
    gemm_bt<1><<<dim3(6, 64), 256, 0, stream>>>(aob, wp, proj_b, 8192, 768, 768,
                                                nullptr, nullptr, nullptr, out);
}

// Round 2
// 201.205 us; speedup vs baseline: 1.3315x; 1.3315x over previous
//
#include <hip/hip_runtime.h>

// Round 2: attention rewritten to swapped-QK^T 32x32 MFMA structure:
//   - S^T = mfma_32x32x16(K_frag, Q_frag): lane owns q-row (q=lane&31),
//     16 scores/lane, keys split across lane-pair (l, l^32).
//   - softmax: in-register reduce + 1 shfl_xor(32); defer-max (THR=8).
//   - P stays in-register: cvt_pk_bf16 + 8 shfl_xor(32) + hi-select (T12).
//   - O^T = mfma_32x32x16(V^T_frag, P^T_frag): rescale lane-local.
//   - no LDS; K/V direct from global (L2/L3-resident); XCD-chunk swizzle.
// GEMMs / converts unchanged from round 1.
// Constants: B=8 N=1024 C=768 H=12 D=64 P=16; BH=96; padded KV MKV=1056 (1040 valid).

typedef __attribute__((ext_vector_type(8))) short short8;
typedef __attribute__((ext_vector_type(4))) float f32x4;
typedef __attribute__((ext_vector_type(16))) float f32x16;
typedef __attribute__((ext_vector_type(4))) int i32x4;

#define GLOAD_LDS16(g, l)                                              \
    __builtin_amdgcn_global_load_lds(                                  \
        (const __attribute__((address_space(1))) void*)(g),            \
        (__attribute__((address_space(3))) void*)(l), 16, 0, 0)

__device__ __forceinline__ unsigned short f2b(float f) {
    unsigned u = __builtin_bit_cast(unsigned, f);
    u = (u + 0x7fffu + ((u >> 16) & 1u)) >> 16;
    return (unsigned short)u;
}

__device__ __forceinline__ int cvt_pk_bf16(float lo, float hi) {
    int r;
    asm("v_cvt_pk_bf16_f32 %0, %1, %2" : "=v"(r) : "v"(lo), "v"(hi));
    return r;
}

// ---------------- f32 -> bf16 convert (vectorized) ----------------
__global__ void cvt_f32_to_bf16(const float* __restrict__ in,
                                unsigned short* __restrict__ out, int n4) {
    int i = blockIdx.x * blockDim.x + threadIdx.x;
    int stride = gridDim.x * blockDim.x;
    for (; i < n4; i += stride) {
        float4 v = reinterpret_cast<const float4*>(in)[i];
        ushort4 o;
        o.x = f2b(v.x); o.y = f2b(v.y); o.z = f2b(v.z); o.w = f2b(v.w);
        reinterpret_cast<ushort4*>(out)[i] = o;
    }
}

// ------------- prefix K/V prefill + pad-row zeroing ----------------
__global__ void prefill(const float* __restrict__ pk, const float* __restrict__ pv,
                        unsigned short* __restrict__ kc, unsigned short* __restrict__ vT) {
    int idx = blockIdx.x * 256 + threadIdx.x;   // 96*32*64 total
    int d  = idx & 63;
    int j  = (idx >> 6) & 31;
    int bh = idx >> 11;
    if (bh >= 96) return;
    int h = bh % 12;
    if (j < 16) {
        kc[((size_t)bh * 1056 + j) * 64 + d]  = f2b(pk[j * 768 + h * 64 + d]);
        vT[((size_t)bh * 64 + d) * 1056 + j]  = f2b(pv[j * 768 + h * 64 + d]);
    } else {
        int row = 1040 + (j - 16);
        kc[((size_t)bh * 1056 + row) * 64 + d] = 0;
        vT[((size_t)bh * 64 + d) * 1056 + row] = 0;
    }
}

// ---------------- GEMM (unchanged round 1) ----------------
template<int MODE>
__global__ __launch_bounds__(256) void gemm_bt(
    const unsigned short* __restrict__ A,
    const unsigned short* __restrict__ W,
    const float* __restrict__ bias,
    int M, int F, int K,
    unsigned short* __restrict__ qbuf,
    unsigned short* __restrict__ kcbuf,
    unsigned short* __restrict__ vtbuf,
    float* __restrict__ fout)
{
    __shared__ __align__(16) unsigned short As[128 * 32];
    __shared__ __align__(16) unsigned short Ws[128 * 32];

    const int tid = threadIdx.x;
    const int m0 = blockIdx.y * 128;
    const int f0 = blockIdx.x * 128;
    const int wid = tid >> 6, lane = tid & 63;
    const int wr = wid >> 1, wc = wid & 1;
    const int lo = lane & 15, hi = lane >> 4;

    f32x4 acc[4][4];
#pragma unroll
    for (int i = 0; i < 4; ++i)
#pragma unroll
        for (int j = 0; j < 4; ++j) acc[i][j] = (f32x4)0.f;

    for (int k0 = 0; k0 < K; k0 += 32) {
#pragma unroll
        for (int j = 0; j < 2; ++j) {
            int e = j * 256 + tid;
            int row = e >> 2, c8 = (e & 3) * 8;
            GLOAD_LDS16(A + (size_t)(m0 + row) * K + k0 + c8, As + e * 8);
            GLOAD_LDS16(W + (size_t)(f0 + row) * K + k0 + c8, Ws + e * 8);
        }
        __syncthreads();

        short8 av[4], wv[4];
#pragma unroll
        for (int mi = 0; mi < 4; ++mi)
            av[mi] = *reinterpret_cast<const short8*>(&As[(wr * 64 + mi * 16 + lo) * 32 + hi * 8]);
#pragma unroll
        for (int ni = 0; ni < 4; ++ni)
            wv[ni] = *reinterpret_cast<const short8*>(&Ws[(wc * 64 + ni * 16 + lo) * 32 + hi * 8]);
#pragma unroll
        for (int mi = 0; mi < 4; ++mi)
#pragma unroll
            for (int ni = 0; ni < 4; ++ni)
                acc[mi][ni] = __builtin_amdgcn_mfma_f32_16x16x32_bf16(av[mi], wv[ni], acc[mi][ni], 0, 0, 0);
        __syncthreads();
    }

#pragma unroll
    for (int mi = 0; mi < 4; ++mi) {
#pragma unroll
        for (int ni = 0; ni < 4; ++ni) {
            int f = f0 + wc * 64 + ni * 16 + lo;
            float bv = bias[f];
#pragma unroll
            for (int r = 0; r < 4; ++r) {
                int m = m0 + wr * 64 + mi * 16 + hi * 4 + r;
                float val = acc[mi][ni][r] + bv;
                if (MODE == 1) {
                    fout[(size_t)m * F + f] = val;
                } else {
                    int b = m >> 10, n = m & 1023;
                    if (f < 768) {
                        int h = f >> 6, d = f & 63;
                        qbuf[((size_t)(b * 12 + h) * 1024 + n) * 64 + d] = f2b(val * 0.125f);
                    } else if (f < 1536) {
                        int f2 = f - 768; int h = f2 >> 6, d = f2 & 63;
                        kcbuf[((size_t)(b * 12 + h) * 1056 + 16 + n) * 64 + d] = f2b(val);
                    } else {
                        int f2 = f - 1536; int h = f2 >> 6, d = f2 & 63;
                        vtbuf[((size_t)(b * 12 + h) * 64 + d) * 1056 + 16 + n] = f2b(val);
                    }
                }
            }
        }
    }
}

// ---------------- flash attention: swapped-QK 32x32, 32 q-rows/wave ----------------
__global__ __launch_bounds__(256) void attn_kernel(
    const unsigned short* __restrict__ q,   // [96][1024][64] (pre-scaled by D^-0.5)
    const unsigned short* __restrict__ kc,  // [96][1056][64]
    const unsigned short* __restrict__ vT,  // [96][64][1056]
    unsigned short* __restrict__ ao)        // [8][1024][768]
{
    const int tid = threadIdx.x;
    const int w = tid >> 6, lane = tid & 63;
    const int ql = lane & 31;               // q index / K row / V^T row
    const int hi = lane >> 5;

    // XCD-chunk swizzle: 768 blocks = 8 XCDs x 96; head gets one XCD's L2.
    const int bid = (blockIdx.x & 7) * 96 + (blockIdx.x >> 3);
    const int head = bid >> 3;              // 0..95
    const int qt = (bid & 7) * 4 + w;       // 0..31 (32-row q tile)
    const int b = head / 12, h = head % 12;

    const unsigned short* qp = q + ((size_t)head * 1024 + qt * 32) * 64;
    const unsigned short* kp = kc + (size_t)head * 1056 * 64;
    const unsigned short* vp = vT + (size_t)head * 64 * 1056;

    // Q fragment (B-operand): lane holds Q[q0+ql][ks*16 + hi*8 + j]
    short8 qf[4];
#pragma unroll
    for (int ks = 0; ks < 4; ++ks)
        qf[ks] = *reinterpret_cast<const short8*>(qp + (size_t)ql * 64 + ks * 16 + hi * 8);

    f32x16 o0 = (f32x16)0.f, o1 = (f32x16)0.f;   // O^T[d][q], d-blocks 0-31 / 32-63
    float m = -1e30f, l = 0.f;

    for (int t = 0; t < 33; ++t) {
        const int kbase = t * 32;
        // ---- S^T = K·Q^T over D=64 (4 mfma) ----
        f32x16 s = (f32x16)0.f;
        __builtin_amdgcn_s_setprio(1);
#pragma unroll
        for (int ks = 0; ks < 4; ++ks) {
            short8 kf = *reinterpret_cast<const short8*>(
                kp + (size_t)(kbase + ql) * 64 + ks * 16 + hi * 8);
            s = __builtin_amdgcn_mfma_f32_32x32x16_bf16(kf, qf[ks], s, 0, 0, 0);
        }
        __builtin_amdgcn_s_setprio(0);

        if (t == 32) {   // keys 1040..1055 invalid -> regs 8..15 (in-tile key >= 16)
#pragma unroll
            for (int r = 8; r < 16; ++r) s[r] = -1e30f;
        }

        // ---- online softmax, lane-local row (q = ql) ----
        float pmax = s[0];
#pragma unroll
        for (int r = 1; r < 16; ++r) pmax = fmaxf(pmax, s[r]);
        pmax = fmaxf(pmax, __shfl_xor(pmax, 32));
        if (!__all(pmax - m <= 8.f)) {       // defer-max (T13)
            float mn = fmaxf(m, pmax);
            float cf = __expf(m - mn);
            l *= cf;
            o0 *= cf;
            o1 *= cf;
            m = mn;
        }
        float p[16];
        float ts = 0.f;
#pragma unroll
        for (int r = 0; r < 16; ++r) { p[r] = __expf(s[r] - m); ts += p[r]; }
        ts += __shfl_xor(ts, 32);
        l += ts;

        // ---- P -> bf16 B-fragments (T12: cvt_pk + cross-half shfl + hi-select) ----
        // lane's p[r] is key (r&3) + 8*(r>>2) + 4*hi (within tile)
        int w0 = cvt_pk_bf16(p[0],  p[1]);   // keys {0,1}+4hi
        int w1 = cvt_pk_bf16(p[2],  p[3]);   // {2,3}+4hi
        int w2 = cvt_pk_bf16(p[4],  p[5]);   // {8,9}+4hi
        int w3 = cvt_pk_bf16(p[6],  p[7]);   // {10,11}+4hi
        int w4 = cvt_pk_bf16(p[8],  p[9]);   // {16,17}+4hi
        int w5 = cvt_pk_bf16(p[10], p[11]);  // {18,19}+4hi
        int w6 = cvt_pk_bf16(p[12], p[13]);  // {24,25}+4hi
        int w7 = cvt_pk_bf16(p[14], p[15]);  // {26,27}+4hi
        int x0 = __shfl_xor(w0, 32), x1 = __shfl_xor(w1, 32);
        int x2 = __shfl_xor(w2, 32), x3 = __shfl_xor(w3, 32);
        int x4 = __shfl_xor(w4, 32), x5 = __shfl_xor(w5, 32);
        int x6 = __shfl_xor(w6, 32), x7 = __shfl_xor(w7, 32);
        i32x4 pw0, pw1;
        pw0[0] = hi ? x2 : w0;  pw0[1] = hi ? x3 : w1;   // mfma#1: k = hi*8 + 0..7
        pw0[2] = hi ? w2 : x0;  pw0[3] = hi ? w3 : x1;
        pw1[0] = hi ? x6 : w4;  pw1[1] = hi ? x7 : w5;   // mfma#2: k = 16 + hi*8 + 0..7
        pw1[2] = hi ? w6 : x4;  pw1[3] = hi ? w7 : x5;
        short8 pf0 = __builtin_bit_cast(short8, pw0);
        short8 pf1 = __builtin_bit_cast(short8, pw1);

        // ---- O^T += V^T · P^T (4 mfma) ----
        short8 vf00 = *reinterpret_cast<const short8*>(vp + (size_t)ql * 1056 + kbase + hi * 8);
        short8 vf01 = *reinterpret_cast<const short8*>(vp + (size_t)ql * 1056 + kbase + 16 + hi * 8);
        short8 vf10 = *reinterpret_cast<const short8*>(vp + (size_t)(32 + ql) * 1056 + kbase + hi * 8);
        short8 vf11 = *reinterpret_cast<const short8*>(vp + (size_t)(32 + ql) * 1056 + kbase + 16 + hi * 8);
        __builtin_amdgcn_s_setprio(1);
        o0 = __builtin_amdgcn_mfma_f32_32x32x16_bf16(vf00, pf0, o0, 0, 0, 0);
        o0 = __builtin_amdgcn_mfma_f32_32x32x16_bf16(vf01, pf1, o0, 0, 0, 0);
        o1 = __builtin_amdgcn_mfma_f32_32x32x16_bf16(vf10, pf0, o1, 0, 0, 0);
        o1 = __builtin_amdgcn_mfma_f32_32x32x16_bf16(vf11, pf1, o1, 0, 0, 0);
        __builtin_amdgcn_s_setprio(0);
    }

    // ---- epilogue: out[q][d], q = ql lane-local, d from regs ----
    const float rinv = 1.f / l;
    unsigned short* aop = ao + ((size_t)b * 1024 + qt * 32 + ql) * 768 + h * 64;
#pragma unroll
    for (int r = 0; r < 16; r += 2) {
        int d = (r & 3) + 8 * (r >> 2) + 4 * hi;
        unsigned lo0 = f2b(o0[r] * rinv), lo1 = f2b(o0[r + 1] * rinv);
        *reinterpret_cast<unsigned*>(aop + d) = lo0 | (lo1 << 16);
        unsigned hi0 = f2b(o1[r] * rinv), hi1 = f2b(o1[r + 1] * rinv);
        *reinterpret_cast<unsigned*>(aop + 32 + d) = hi0 | (hi1 << 16);
    }
}

extern "C" void kernel_launch(void* const* d_in, const int* in_sizes, int n_in,
                              void* d_out, int out_size, void* d_ws, size_t ws_size,
                              hipStream_t stream) {
    const float* x        = (const float*)d_in[0];
    const float* qkv_w    = (const float*)d_in[1];
    const float* qkv_b    = (const float*)d_in[2];
    const float* proj_w   = (const float*)d_in[3];
    const float* proj_b   = (const float*)d_in[4];
    const float* prefix_k = (const float*)d_in[5];
    const float* prefix_v = (const float*)d_in[6];
    float* out = (float*)d_out;

    char* ws = (char*)d_ws;
    unsigned short* xb   = (unsigned short*)(ws);               // 8192*768 bf16
    unsigned short* wqkv = (unsigned short*)(ws + 12582912);    // 2304*768
    unsigned short* wp   = (unsigned short*)(ws + 16121856);    // 768*768
    unsigned short* qb   = (unsigned short*)(ws + 17301504);    // 96*1024*64
    unsigned short* kcb  = (unsigned short*)(ws + 29884416);    // 96*1056*64
    unsigned short* vtb  = (unsigned short*)(ws + 42860544);    // 96*64*1056
    unsigned short* aob  = xb;                                  // reuse xb after QKV GEMM

    cvt_f32_to_bf16<<<1024, 256, 0, stream>>>(x, xb, 8192 * 768 / 4);
    cvt_f32_to_bf16<<<512, 256, 0, stream>>>(qkv_w, wqkv, 2304 * 768 / 4);
    cvt_f32_to_bf16<<<256, 256, 0, stream>>>(proj_w, wp, 768 * 768 / 4);
    prefill<<<768, 256, 0, stream>>>(prefix_k, prefix_v, kcb, vtb);

    gemm_bt<0><<<dim3(18, 64), 256, 0, stream>>>(xb, wqkv, qkv_b, 8192, 2304, 768,
                                                 qb, kcb, vtb, nullptr);
    attn_kernel<<<768, 256, 0, stream>>>(qb, kcb, vtb, aob);
    gemm_bt<1><<<dim3(6, 64), 256, 0, stream>>>(aob, wp, proj_b, 8192, 768, 768,
                                                nullptr, nullptr, nullptr, out);
}

// Round 3
// 180.698 us; speedup vs baseline: 1.4826x; 1.1135x over previous
//
#include <hip/hip_runtime.h>

// Round 3: GEMMs get (a) double-buffered 2-phase K-loop (stage t+1 before
//          compute t, single barrier per step), (b) XCD-chunked block swizzle
//          (1-D grid, 144/48 consecutive tiles per XCD -> A-panel L2 locality).
// Attention (swapped-QK 32x32, in-register softmax) unchanged from round 2.
// Constants: B=8 N=1024 C=768 H=12 D=64 P=16; BH=96; padded KV MKV=1056 (1040 valid).

typedef __attribute__((ext_vector_type(8))) short short8;
typedef __attribute__((ext_vector_type(4))) float f32x4;
typedef __attribute__((ext_vector_type(16))) float f32x16;
typedef __attribute__((ext_vector_type(4))) int i32x4;

#define GLOAD_LDS16(g, l)                                              \
    __builtin_amdgcn_global_load_lds(                                  \
        (const __attribute__((address_space(1))) void*)(g),            \
        (__attribute__((address_space(3))) void*)(l), 16, 0, 0)

__device__ __forceinline__ unsigned short f2b(float f) {
    unsigned u = __builtin_bit_cast(unsigned, f);
    u = (u + 0x7fffu + ((u >> 16) & 1u)) >> 16;
    return (unsigned short)u;
}

__device__ __forceinline__ int cvt_pk_bf16(float lo, float hi) {
    int r;
    asm("v_cvt_pk_bf16_f32 %0, %1, %2" : "=v"(r) : "v"(lo), "v"(hi));
    return r;
}

// ---------------- f32 -> bf16 convert (vectorized) ----------------
__global__ void cvt_f32_to_bf16(const float* __restrict__ in,
                                unsigned short* __restrict__ out, int n4) {
    int i = blockIdx.x * blockDim.x + threadIdx.x;
    int stride = gridDim.x * blockDim.x;
    for (; i < n4; i += stride) {
        float4 v = reinterpret_cast<const float4*>(in)[i];
        ushort4 o;
        o.x = f2b(v.x); o.y = f2b(v.y); o.z = f2b(v.z); o.w = f2b(v.w);
        reinterpret_cast<ushort4*>(out)[i] = o;
    }
}

// ------------- prefix K/V prefill + pad-row zeroing ----------------
__global__ void prefill(const float* __restrict__ pk, const float* __restrict__ pv,
                        unsigned short* __restrict__ kc, unsigned short* __restrict__ vT) {
    int idx = blockIdx.x * 256 + threadIdx.x;   // 96*32*64 total
    int d  = idx & 63;
    int j  = (idx >> 6) & 31;
    int bh = idx >> 11;
    if (bh >= 96) return;
    int h = bh % 12;
    if (j < 16) {
        kc[((size_t)bh * 1056 + j) * 64 + d]  = f2b(pk[j * 768 + h * 64 + d]);
        vT[((size_t)bh * 64 + d) * 1056 + j]  = f2b(pv[j * 768 + h * 64 + d]);
    } else {
        int row = 1040 + (j - 16);
        kc[((size_t)bh * 1056 + row) * 64 + d] = 0;
        vT[((size_t)bh * 64 + d) * 1056 + row] = 0;
    }
}

// ---------------- GEMM:  Y[m][f] = sum_k A[m][k] * W[f][k] + bias[f] ----------------
// 128x128 tile, BK=32, 4 waves (2x2), double-buffered LDS, 1-D swizzled grid.
// FT = number of f-tiles (grid = MT*FT, both grid%8==0).
template<int MODE, int FT>
__global__ __launch_bounds__(256) void gemm_bt(
    const unsigned short* __restrict__ A,   // [M][K] bf16
    const unsigned short* __restrict__ W,   // [F][K] bf16
    const float* __restrict__ bias,         // [F]
    int M, int F, int K,
    unsigned short* __restrict__ qbuf,      // [96][1024][64]
    unsigned short* __restrict__ kcbuf,     // [96][1056][64]
    unsigned short* __restrict__ vtbuf,     // [96][64][1056]
    float* __restrict__ fout)               // [M][F]
{
    __shared__ __align__(16) unsigned short As[2][128 * 32];
    __shared__ __align__(16) unsigned short Ws[2][128 * 32];

    const int tid = threadIdx.x;
    // XCD-chunk swizzle: consecutive chunk of tiles per XCD (bijective, nwg%8==0)
    const int bid = (blockIdx.x & 7) * (gridDim.x >> 3) + (blockIdx.x >> 3);
    const int m0 = (bid / FT) * 128;
    const int f0 = (bid % FT) * 128;
    const int wid = tid >> 6, lane = tid & 63;
    const int wr = wid >> 1, wc = wid & 1;
    const int lo = lane & 15, hi = lane >> 4;

    f32x4 acc[4][4];
#pragma unroll
    for (int i = 0; i < 4; ++i)
#pragma unroll
        for (int j = 0; j < 4; ++j) acc[i][j] = (f32x4)0.f;

    const int nt = K >> 5;   // 24

    // prologue: stage tile 0 into buffer 0
#pragma unroll
    for (int j = 0; j < 2; ++j) {
        int e = j * 256 + tid;
        int row = e >> 2, c8 = (e & 3) * 8;
        GLOAD_LDS16(A + (size_t)(m0 + row) * K + c8, &As[0][e * 8]);
        GLOAD_LDS16(W + (size_t)(f0 + row) * K + c8, &Ws[0][e * 8]);
    }
    __syncthreads();

    int cur = 0;
    for (int t = 0; t < nt; ++t) {
        // stage next tile into the other buffer (overlaps with compute below)
        if (t + 1 < nt) {
            int k0 = (t + 1) << 5;
#pragma unroll
            for (int j = 0; j < 2; ++j) {
                int e = j * 256 + tid;
                int row = e >> 2, c8 = (e & 3) * 8;
                GLOAD_LDS16(A + (size_t)(m0 + row) * K + k0 + c8, &As[cur ^ 1][e * 8]);
                GLOAD_LDS16(W + (size_t)(f0 + row) * K + k0 + c8, &Ws[cur ^ 1][e * 8]);
            }
        }

        short8 av[4], wv[4];
#pragma unroll
        for (int mi = 0; mi < 4; ++mi)
            av[mi] = *reinterpret_cast<const short8*>(&As[cur][(wr * 64 + mi * 16 + lo) * 32 + hi * 8]);
#pragma unroll
        for (int ni = 0; ni < 4; ++ni)
            wv[ni] = *reinterpret_cast<const short8*>(&Ws[cur][(wc * 64 + ni * 16 + lo) * 32 + hi * 8]);
#pragma unroll
        for (int mi = 0; mi < 4; ++mi)
#pragma unroll
            for (int ni = 0; ni < 4; ++ni)
                acc[mi][ni] = __builtin_amdgcn_mfma_f32_16x16x32_bf16(av[mi], wv[ni], acc[mi][ni], 0, 0, 0);

        __syncthreads();   // drains next-tile loads; all waves done reading cur
        cur ^= 1;
    }

    // epilogue: D row = hi*4 + r, col = lo  (within each 16x16 tile)
#pragma unroll
    for (int mi = 0; mi < 4; ++mi) {
#pragma unroll
        for (int ni = 0; ni < 4; ++ni) {
            int f = f0 + wc * 64 + ni * 16 + lo;
            float bv = bias[f];
#pragma unroll
            for (int r = 0; r < 4; ++r) {
                int m = m0 + wr * 64 + mi * 16 + hi * 4 + r;
                float val = acc[mi][ni][r] + bv;
                if (MODE == 1) {
                    fout[(size_t)m * F + f] = val;
                } else {
                    int b = m >> 10, n = m & 1023;
                    if (f < 768) {
                        int h = f >> 6, d = f & 63;
                        qbuf[((size_t)(b * 12 + h) * 1024 + n) * 64 + d] = f2b(val * 0.125f);
                    } else if (f < 1536) {
                        int f2 = f - 768; int h = f2 >> 6, d = f2 & 63;
                        kcbuf[((size_t)(b * 12 + h) * 1056 + 16 + n) * 64 + d] = f2b(val);
                    } else {
                        int f2 = f - 1536; int h = f2 >> 6, d = f2 & 63;
                        vtbuf[((size_t)(b * 12 + h) * 64 + d) * 1056 + 16 + n] = f2b(val);
                    }
                }
            }
        }
    }
}

// ---------------- flash attention: swapped-QK 32x32, 32 q-rows/wave ----------------
__global__ __launch_bounds__(256) void attn_kernel(
    const unsigned short* __restrict__ q,   // [96][1024][64] (pre-scaled by D^-0.5)
    const unsigned short* __restrict__ kc,  // [96][1056][64]
    const unsigned short* __restrict__ vT,  // [96][64][1056]
    unsigned short* __restrict__ ao)        // [8][1024][768]
{
    const int tid = threadIdx.x;
    const int w = tid >> 6, lane = tid & 63;
    const int ql = lane & 31;               // q index / K row / V^T row
    const int hi = lane >> 5;

    // XCD-chunk swizzle: 768 blocks = 8 XCDs x 96; head gets one XCD's L2.
    const int bid = (blockIdx.x & 7) * 96 + (blockIdx.x >> 3);
    const int head = bid >> 3;              // 0..95
    const int qt = (bid & 7) * 4 + w;       // 0..31 (32-row q tile)
    const int b = head / 12, h = head % 12;

    const unsigned short* qp = q + ((size_t)head * 1024 + qt * 32) * 64;
    const unsigned short* kp = kc + (size_t)head * 1056 * 64;
    const unsigned short* vp = vT + (size_t)head * 64 * 1056;

    // Q fragment (B-operand): lane holds Q[q0+ql][ks*16 + hi*8 + j]
    short8 qf[4];
#pragma unroll
    for (int ks = 0; ks < 4; ++ks)
        qf[ks] = *reinterpret_cast<const short8*>(qp + (size_t)ql * 64 + ks * 16 + hi * 8);

    f32x16 o0 = (f32x16)0.f, o1 = (f32x16)0.f;   // O^T[d][q], d-blocks 0-31 / 32-63
    float m = -1e30f, l = 0.f;

    for (int t = 0; t < 33; ++t) {
        const int kbase = t * 32;
        // ---- S^T = K·Q^T over D=64 (4 mfma) ----
        f32x16 s = (f32x16)0.f;
        __builtin_amdgcn_s_setprio(1);
#pragma unroll
        for (int ks = 0; ks < 4; ++ks) {
            short8 kf = *reinterpret_cast<const short8*>(
                kp + (size_t)(kbase + ql) * 64 + ks * 16 + hi * 8);
            s = __builtin_amdgcn_mfma_f32_32x32x16_bf16(kf, qf[ks], s, 0, 0, 0);
        }
        __builtin_amdgcn_s_setprio(0);

        if (t == 32) {   // keys 1040..1055 invalid -> regs 8..15 (in-tile key >= 16)
#pragma unroll
            for (int r = 8; r < 16; ++r) s[r] = -1e30f;
        }

        // ---- online softmax, lane-local row (q = ql) ----
        float pmax = s[0];
#pragma unroll
        for (int r = 1; r < 16; ++r) pmax = fmaxf(pmax, s[r]);
        pmax = fmaxf(pmax, __shfl_xor(pmax, 32));
        if (!__all(pmax - m <= 8.f)) {       // defer-max (T13)
            float mn = fmaxf(m, pmax);
            float cf = __expf(m - mn);
            l *= cf;
            o0 *= cf;
            o1 *= cf;
            m = mn;
        }
        float p[16];
        float ts = 0.f;
#pragma unroll
        for (int r = 0; r < 16; ++r) { p[r] = __expf(s[r] - m); ts += p[r]; }
        ts += __shfl_xor(ts, 32);
        l += ts;

        // ---- P -> bf16 B-fragments (T12: cvt_pk + cross-half shfl + hi-select) ----
        int w0 = cvt_pk_bf16(p[0],  p[1]);
        int w1 = cvt_pk_bf16(p[2],  p[3]);
        int w2 = cvt_pk_bf16(p[4],  p[5]);
        int w3 = cvt_pk_bf16(p[6],  p[7]);
        int w4 = cvt_pk_bf16(p[8],  p[9]);
        int w5 = cvt_pk_bf16(p[10], p[11]);
        int w6 = cvt_pk_bf16(p[12], p[13]);
        int w7 = cvt_pk_bf16(p[14], p[15]);
        int x0 = __shfl_xor(w0, 32), x1 = __shfl_xor(w1, 32);
        int x2 = __shfl_xor(w2, 32), x3 = __shfl_xor(w3, 32);
        int x4 = __shfl_xor(w4, 32), x5 = __shfl_xor(w5, 32);
        int x6 = __shfl_xor(w6, 32), x7 = __shfl_xor(w7, 32);
        i32x4 pw0, pw1;
        pw0[0] = hi ? x2 : w0;  pw0[1] = hi ? x3 : w1;
        pw0[2] = hi ? w2 : x0;  pw0[3] = hi ? w3 : x1;
        pw1[0] = hi ? x6 : w4;  pw1[1] = hi ? x7 : w5;
        pw1[2] = hi ? w6 : x4;  pw1[3] = hi ? w7 : x5;
        short8 pf0 = __builtin_bit_cast(short8, pw0);
        short8 pf1 = __builtin_bit_cast(short8, pw1);

        // ---- O^T += V^T · P^T (4 mfma) ----
        short8 vf00 = *reinterpret_cast<const short8*>(vp + (size_t)ql * 1056 + kbase + hi * 8);
        short8 vf01 = *reinterpret_cast<const short8*>(vp + (size_t)ql * 1056 + kbase + 16 + hi * 8);
        short8 vf10 = *reinterpret_cast<const short8*>(vp + (size_t)(32 + ql) * 1056 + kbase + hi * 8);
        short8 vf11 = *reinterpret_cast<const short8*>(vp + (size_t)(32 + ql) * 1056 + kbase + 16 + hi * 8);
        __builtin_amdgcn_s_setprio(1);
        o0 = __builtin_amdgcn_mfma_f32_32x32x16_bf16(vf00, pf0, o0, 0, 0, 0);
        o0 = __builtin_amdgcn_mfma_f32_32x32x16_bf16(vf01, pf1, o0, 0, 0, 0);
        o1 = __builtin_amdgcn_mfma_f32_32x32x16_bf16(vf10, pf0, o1, 0, 0, 0);
        o1 = __builtin_amdgcn_mfma_f32_32x32x16_bf16(vf11, pf1, o1, 0, 0, 0);
        __builtin_amdgcn_s_setprio(0);
    }

    // ---- epilogue: out[q][d], q = ql lane-local, d from regs ----
    const float rinv = 1.f / l;
    unsigned short* aop = ao + ((size_t)b * 1024 + qt * 32 + ql) * 768 + h * 64;
#pragma unroll
    for (int r = 0; r < 16; r += 2) {
        int d = (r & 3) + 8 * (r >> 2) + 4 * hi;
        unsigned lo0 = f2b(o0[r] * rinv), lo1 = f2b(o0[r + 1] * rinv);
        *reinterpret_cast<unsigned*>(aop + d) = lo0 | (lo1 << 16);
        unsigned hi0 = f2b(o1[r] * rinv), hi1 = f2b(o1[r + 1] * rinv);
        *reinterpret_cast<unsigned*>(aop + 32 + d) = hi0 | (hi1 << 16);
    }
}

extern "C" void kernel_launch(void* const* d_in, const int* in_sizes, int n_in,
                              void* d_out, int out_size, void* d_ws, size_t ws_size,
                              hipStream_t stream) {
    const float* x        = (const float*)d_in[0];
    const float* qkv_w    = (const float*)d_in[1];
    const float* qkv_b    = (const float*)d_in[2];
    const float* proj_w   = (const float*)d_in[3];
    const float* proj_b   = (const float*)d_in[4];
    const float* prefix_k = (const float*)d_in[5];
    const float* prefix_v = (const float*)d_in[6];
    float* out = (float*)d_out;

    char* ws = (char*)d_ws;
    unsigned short* xb   = (unsigned short*)(ws);               // 8192*768 bf16
    unsigned short* wqkv = (unsigned short*)(ws + 12582912);    // 2304*768
    unsigned short* wp   = (unsigned short*)(ws + 16121856);    // 768*768
    unsigned short* qb   = (unsigned short*)(ws + 17301504);    // 96*1024*64
    unsigned short* kcb  = (unsigned short*)(ws + 29884416);    // 96*1056*64
    unsigned short* vtb  = (unsigned short*)(ws + 42860544);    // 96*64*1056
    unsigned short* aob  = xb;                                  // reuse xb after QKV GEMM

    cvt_f32_to_bf16<<<1024, 256, 0, stream>>>(x, xb, 8192 * 768 / 4);
    cvt_f32_to_bf16<<<512, 256, 0, stream>>>(qkv_w, wqkv, 2304 * 768 / 4);
    cvt_f32_to_bf16<<<256, 256, 0, stream>>>(proj_w, wp, 768 * 768 / 4);
    prefill<<<768, 256, 0, stream>>>(prefix_k, prefix_v, kcb, vtb);

    // QKV: 64 m-tiles x 18 f-tiles = 1152 blocks (1152%8==0)
    gemm_bt<0, 18><<<1152, 256, 0, stream>>>(xb, wqkv, qkv_b, 8192, 2304, 768,
                                             qb, kcb, vtb, nullptr);
    attn_kernel<<<768, 256, 0, stream>>>(qb, kcb, vtb, aob);
    // proj: 64 m-tiles x 6 f-tiles = 384 blocks (384%8==0)
    gemm_bt<1, 6><<<384, 256, 0, stream>>>(aob, wp, proj_b, 8192, 768, 768,
                                           nullptr, nullptr, nullptr, out);
}